// Round 11
// baseline (240.908 us; speedup 1.0000x reference)
//
#include <hip/hip_runtime.h>

// LHGConv2d: transpose -> FCM (3 iters) -> top5 -> fused edge/cluster/linear.
// R3: k_m2 16-wave blocks 71->19us. R5: k_m1/top5 cluster-sliced. VERIFIED.
// R9: k_out load-batching 59->46us (VGPR theory wrong; batching was the win).
// R10: (1) k_out phase-B lane=n via s_feat LDS + s_load W (kills 1536
//      readlanes/wave, removes W prologue); (2) umT[k][n] layout: k_m1 writes
//      coalesced, k_m2 scalar streams contiguous (dwordx4 per 4 points).

constexpr int B  = 4;
constexpr int C  = 64;
constexpr int N  = 8192;
constexpr int KE = 16;    // graph neighbors
constexpr int OC = 64;
constexpr int NC = 50;    // num_clusters
constexpr int TC = 5;     // top_clusters
constexpr int C3 = 192;   // 3*C
constexpr int KG  = 5;    // clusters per k_m2 block
constexpr int NKG = 10;   // NC/KG
constexpr int NS  = 8;    // n-slices for deterministic partial reduction
constexpr int MW  = 16;   // waves per k_m2 block
constexpr float FEPS = 1e-8f;

// ---------------------------------------------------------------- transpose
__global__ __launch_bounds__(256) void k_transpose(const float* __restrict__ x,
                                                   float* __restrict__ xt,
                                                   float* __restrict__ xn) {
  __shared__ float tile[64][65];           // +1 pad: conflict-free transpose
  int b  = blockIdx.x >> 7;                // 128 tiles per batch
  int n0 = (blockIdx.x & 127) << 6;
  int tid = threadIdx.x;
  int nl = tid & 63, cq = tid >> 6;
#pragma unroll
  for (int r = 0; r < 16; ++r) {
    int cc = r * 4 + cq;
    tile[cc][nl] = x[((size_t)b * C + cc) * N + n0 + nl];
  }
  __syncthreads();
  int cl = tid & 63, nq = tid >> 6;
#pragma unroll
  for (int r = 0; r < 16; ++r) {
    int nr = r * 4 + nq;
    xt[((size_t)b * N + n0 + nr) * C + cl] = tile[cl][nr];
  }
  if (tid < 64) {
    float s = 0.f;
#pragma unroll
    for (int cc = 0; cc < 64; ++cc) { float v = tile[cc][tid]; s = fmaf(v, v, s); }
    xn[(size_t)b * N + n0 + tid] = s;
  }
}

// ---------------------------------------------------------------- init cent
__global__ __launch_bounds__(256) void k_init(const float* __restrict__ xt,
                                              float* __restrict__ cent,
                                              float* __restrict__ cn) {
  int i = blockIdx.x * 256 + threadIdx.x;  // 0 .. B*NC*C-1 (12800)
  int lane = threadIdx.x & 63;
  int ccol = i & 63;
  int row  = i >> 6;                       // b*NC + k
  int k = row % NC, b = row / NC;
  int src = (k * (N - 1)) / (NC - 1);      // linspace().astype(int32)
  float v = xt[((size_t)b * N + src) * C + ccol];
  cent[i] = v;
  float sq = v * v;
#pragma unroll
  for (int off = 32; off; off >>= 1) sq += __shfl_down(sq, off, 64);
  if (lane == 0) cn[row] = sq;
}

// ---------------------------------------------------------------- membership
// 8 waves share 64 points; wave w computes a 6-7 cluster slice. R10: writes
// umT[b][k][n] (transposed) -> per-j stores are 64-lane coalesced 256B rows.
__global__ __launch_bounds__(512) void k_m1(const float* __restrict__ xt,
                                            const float* __restrict__ xn,
                                            const float* __restrict__ cent,
                                            const float* __restrict__ cn,
                                            float* __restrict__ umT) {
  int gid = blockIdx.x;                    // 512 blocks
  int xcd = gid & 7;
  int b = xcd >> 1;                        // 2 XCDs per batch
  int chunk = ((gid >> 3) << 1) + (xcd & 1);  // 0..127
  int n0 = chunk << 6;                     // 64 points
  int w = __builtin_amdgcn_readfirstlane((int)threadIdx.x >> 6);  // 0..7
  int lane = threadIdx.x & 63;
  int n = n0 + lane;
  int base = (w < 2) ? 7 * w : 14 + 6 * (w - 2);
  int cnt  = (w < 2) ? 7 : 6;
  const float* xr = xt + ((size_t)b * N + n) * C;
  const float* cb = cent + b * NC * C;
  float dot[7];
#pragma unroll
  for (int j = 0; j < 7; ++j) dot[j] = 0.f;
  for (int c4 = 0; c4 < C; c4 += 4) {
    float4 xv = *(const float4*)(xr + c4);
#pragma unroll
    for (int j = 0; j < 7; ++j) {
      int kk = base + j; kk = (kk < NC) ? kk : 0;  // uniform clamp (wave 7, j=6)
      float4 cv = *(const float4*)(cb + kk * C + c4);  // uniform -> s_load
      dot[j] = fmaf(xv.x, cv.x, dot[j]);
      dot[j] = fmaf(xv.y, cv.y, dot[j]);
      dot[j] = fmaf(xv.z, cv.z, dot[j]);
      dot[j] = fmaf(xv.w, cv.w, dot[j]);
    }
  }
  float xnv = xn[(size_t)b * N + n];
  const float* cnb = cn + b * NC;
  float inv[7];
  float psum = 0.f;
#pragma unroll
  for (int j = 0; j < 7; ++j) {
    int kk = base + j; kk = (kk < NC) ? kk : 0;
    float d2 = fmaf(-2.f, dot[j], xnv + cnb[kk]);
    d2 = fmaxf(d2, FEPS);
    float iv = 1.f / d2;
    inv[j] = iv;
    psum += (j < cnt) ? iv : 0.f;
  }
  __shared__ float s_ps[8][64];
  s_ps[w][lane] = psum;
  __syncthreads();
  float ssum = 0.f;
#pragma unroll
  for (int ww = 0; ww < 8; ++ww) ssum += s_ps[ww][lane];  // fixed order
  float s2i = 1.f / (ssum * ssum);
  float* upT = umT + ((size_t)b * NC + base) * N + n;
#pragma unroll
  for (int j = 0; j < 7; ++j)
    if (j < cnt) upT[(size_t)j * N] = inv[j] * inv[j] * s2i;  // coalesced row
}

// ---------------------------------------------------------------- update GEMM
// partial[s][b][k][c] = sum_{n in slice s} um[n][k] * xt[n][c]  (deterministic)
// R10: umT layout -> wave w owns a CONTIGUOUS 64-n chunk; u values come as
// s_load dwordx4 (4 points per load per cluster), scalar-cache friendly.
__global__ __launch_bounds__(1024) void k_m2(const float* __restrict__ umT,
                                             const float* __restrict__ xt,
                                             float* __restrict__ part_c,
                                             float* __restrict__ part_u) {
  int gid = blockIdx.x;                    // B*NKG*NS = 320
  int xcd = gid & 7;
  int b = xcd >> 1;
  int r = ((gid >> 3) << 1) + (xcd & 1);   // 0..79
  int kg = r >> 3;                         // 0..9
  int s  = r & 7;                          // 0..7
  int k0 = kg * KG;
  int w = __builtin_amdgcn_readfirstlane((int)threadIdx.x >> 6);  // wave 0..15
  int c = threadIdx.x & 63;
  int sn0 = s * (N / NS);                  // 1024-point slice
  int nb = w * 64;                         // contiguous 64-n chunk for wave w
  const float* uT = umT + ((size_t)b * NC + k0) * N + sn0 + nb;
  const float* xb = xt + ((size_t)(b * N + sn0 + nb)) * C + c;
  float acc[KG], ua[KG];
#pragma unroll
  for (int j = 0; j < KG; ++j) { acc[j] = 0.f; ua[j] = 0.f; }
  for (int n4 = 0; n4 < 64; n4 += 4) {
    float4 u4[KG];
#pragma unroll
    for (int j = 0; j < KG; ++j)
      u4[j] = *(const float4*)(uT + (size_t)j * N + n4);  // uniform -> s_load x4
#pragma unroll
    for (int t = 0; t < 4; ++t) {
      float xv = xb[(size_t)(n4 + t) * C];
#pragma unroll
      for (int j = 0; j < KG; ++j) {
        float u = (t == 0) ? u4[j].x : (t == 1) ? u4[j].y : (t == 2) ? u4[j].z : u4[j].w;
        acc[j] = fmaf(u, xv, acc[j]);
        ua[j] += u;
      }
    }
  }
  __shared__ float s_acc[MW][KG][64];      // 20 KiB
  __shared__ float s_ua[MW][KG];
#pragma unroll
  for (int j = 0; j < KG; ++j) s_acc[w][j][c] = acc[j];
  if (c == 0) {
#pragma unroll
    for (int j = 0; j < KG; ++j) s_ua[w][j] = ua[j];
  }
  __syncthreads();
  if (w == 0) {
#pragma unroll
    for (int j = 0; j < KG; ++j) {
      float t = 0.f;
#pragma unroll
      for (int ww = 0; ww < MW; ++ww) t += s_acc[ww][j][c];  // fixed order
      part_c[((size_t)s * (B * NC) + b * NC + k0 + j) * C + c] = t;
    }
    if (c == 0) {
#pragma unroll
      for (int j = 0; j < KG; ++j) {
        float t = 0.f;
#pragma unroll
        for (int ww = 0; ww < MW; ++ww) t += s_ua[ww][j];
        part_u[(size_t)s * (B * NC) + b * NC + k0 + j] = t;
      }
    }
  }
}

// ---------------------------------------------------------------- reduce+norm
__global__ __launch_bounds__(256) void k_m3(const float* __restrict__ part_c,
                                            const float* __restrict__ part_u,
                                            float* __restrict__ cent,
                                            float* __restrict__ cn) {
  int i = blockIdx.x * 256 + threadIdx.x;  // 12800
  int lane = threadIdx.x & 63;
  int row = i >> 6;
  float tot = 0.f;
#pragma unroll
  for (int s = 0; s < NS; ++s) tot += part_c[(size_t)s * (B * NC * C) + i];
  float us = 0.f;
#pragma unroll
  for (int s = 0; s < NS; ++s) us += part_u[(size_t)s * (B * NC) + row];
  float v = tot / (us + FEPS);
  cent[i] = v;
  float sq = v * v;
#pragma unroll
  for (int off = 32; off; off >>= 1) sq += __shfl_down(sq, off, 64);
  if (lane == 0) cn[row] = sq;
}

// ---------------------------------------------------------------- top-5
__global__ __launch_bounds__(512) void k_top5(const float* __restrict__ xt,
                                              const float* __restrict__ xn,
                                              const float* __restrict__ cent,
                                              const float* __restrict__ cn,
                                              int* __restrict__ t5) {
  int gid = blockIdx.x;                    // 512 blocks
  int xcd = gid & 7;
  int b = xcd >> 1;
  int chunk = ((gid >> 3) << 1) + (xcd & 1);  // 0..127
  int n0 = chunk << 6;
  int w = __builtin_amdgcn_readfirstlane((int)threadIdx.x >> 6);  // 0..7
  int lane = threadIdx.x & 63;
  int n = n0 + lane;
  int base = (w < 2) ? 7 * w : 14 + 6 * (w - 2);
  int cnt  = (w < 2) ? 7 : 6;
  const float* xr = xt + ((size_t)b * N + n) * C;
  const float* cb = cent + b * NC * C;
  float dot[7];
#pragma unroll
  for (int j = 0; j < 7; ++j) dot[j] = 0.f;
  for (int c4 = 0; c4 < C; c4 += 4) {
    float4 xv = *(const float4*)(xr + c4);
#pragma unroll
    for (int j = 0; j < 7; ++j) {
      int kk = base + j; kk = (kk < NC) ? kk : 0;
      float4 cv = *(const float4*)(cb + kk * C + c4);  // uniform -> s_load
      dot[j] = fmaf(xv.x, cv.x, dot[j]);
      dot[j] = fmaf(xv.y, cv.y, dot[j]);
      dot[j] = fmaf(xv.z, cv.z, dot[j]);
      dot[j] = fmaf(xv.w, cv.w, dot[j]);
    }
  }
  float xnv = xn[(size_t)b * N + n];
  const float* cnb = cn + b * NC;
  __shared__ float s_inv[NC][65];          // 13 KiB; [k][point]
#pragma unroll
  for (int j = 0; j < 7; ++j) {
    int kk = base + j; kk = (kk < NC) ? kk : 0;
    float d2 = fmaxf(fmaf(-2.f, dot[j], xnv + cnb[kk]), FEPS);
    float iv = 1.f / d2;
    if (j < cnt) s_inv[base + j][lane] = iv;
  }
  __syncthreads();
  if (w == 0) {
    float v[NC];
#pragma unroll
    for (int k = 0; k < NC; ++k) v[k] = s_inv[k][lane];  // conflict-free row read
    unsigned long long taken = 0ull;
    int* tp = t5 + ((size_t)b * N + n) * TC;
#pragma unroll
    for (int t = 0; t < TC; ++t) {
      float best = -1.f;
      int bi = 0;
#pragma unroll
      for (int k = 0; k < NC; ++k) {
        bool ok = (((taken >> k) & 1ull) == 0ull) && (v[k] > best);
        best = ok ? v[k] : best;
        bi   = ok ? k : bi;
      }
      taken |= (1ull << bi);
      tp[t] = bi;
    }
  }
}

// ---------------------------------------------------------------- fused output
// R10: phase A (lane=c, batched gathers) writes features to s_feat[192][65].
// Phase B flips to lane=n: wave wv computes o in [8wv,8wv+8) over 64 points;
// W/bias via wave-uniform s_load (no readlane, no W LDS staging). f-ascending
// fma order == previous (3cp+s, s inner) -> bit-identical output.
__global__ __launch_bounds__(512, 4) void k_out(const float* __restrict__ xt,
                                                const float* __restrict__ cent,
                                                const float* __restrict__ W,
                                                const int* __restrict__ t5,
                                                const int* __restrict__ eidx,
                                                const float* __restrict__ bias,
                                                float* __restrict__ out) {
  __shared__ float s_feat[C3][65];         // 49.9 KB; bank-alias 2-way (free)
  int tid = threadIdx.x;
  int gid = blockIdx.x;                    // 512 blocks
  int xcd = gid & 7;
  int b = xcd >> 1;
  int chunk = ((gid >> 3) << 1) + (xcd & 1);  // 0..127 (64 points each)
  int wv = __builtin_amdgcn_readfirstlane(tid >> 6);  // 0..7
  int lane = tid & 63;
  int n0 = chunk * 64;
  int nw0 = n0 + wv * 8;                   // phase-A points for this wave
  const float* xtb = xt + ((size_t)b * N) * C;
  const float* cb  = cent + b * NC * C;
  const int* e0b = eidx + ((size_t)b * N) * KE;
  const int* e1b = eidx + ((size_t)(B + b) * N) * KE;
  int c = lane;
  int fr = wv * 8;
#pragma unroll
  for (int j = 0; j < 8; ++j) {
    int n = nw0 + j;
    const int* p0 = e0b + (size_t)n * KE;  // uniform -> s_load
    const int* p1 = e1b + (size_t)n * KE;
    const int* tp = t5 + ((size_t)b * N + n) * TC;
    // issue ALL loads for this point first (38 live results)
    float x0 = xtb[(size_t)n * C + c];
    float g0[KE], g1[KE];
#pragma unroll
    for (int k = 0; k < KE; ++k) {
      g0[k] = xtb[(size_t)p0[k] * C + c];
      g1[k] = xtb[(size_t)p1[k] * C + c];
    }
    float cv[TC];
#pragma unroll
    for (int t = 0; t < TC; ++t) cv[t] = cb[(size_t)tp[t] * C + c];
    // consume (fmax order unchanged)
    float m1 = g0[0] - g1[0];
#pragma unroll
    for (int k = 1; k < KE; ++k) m1 = fmaxf(m1, g0[k] - g1[k]);
    float cm = cv[0];
#pragma unroll
    for (int t = 1; t < TC; ++t) cm = fmaxf(cm, cv[t]);
    s_feat[3 * c + 0][fr + j] = x0;
    s_feat[3 * c + 1][fr + j] = m1;
    s_feat[3 * c + 2][fr + j] = cm - x0;
  }
  __syncthreads();
  int o0 = wv * 8;
  float acc[8];
#pragma unroll
  for (int oj = 0; oj < 8; ++oj) acc[oj] = bias[o0 + oj];  // uniform -> s_load
#pragma unroll 4
  for (int f = 0; f < C3; ++f) {
    float v = s_feat[f][lane];
#pragma unroll
    for (int oj = 0; oj < 8; ++oj)
      acc[oj] = fmaf(W[(size_t)(o0 + oj) * C3 + f], v, acc[oj]);  // W: s_load
  }
  float* ob = out + ((size_t)b * OC + o0) * N + n0 + lane;
#pragma unroll
  for (int oj = 0; oj < 8; ++oj)
    ob[(size_t)oj * N] = fmaxf(acc[oj], 0.f);  // coalesced 256B per o
}

// ----------------------------------------------------------------------------
extern "C" void kernel_launch(void* const* d_in, const int* in_sizes, int n_in,
                              void* d_out, int out_size, void* d_ws, size_t ws_size,
                              hipStream_t stream) {
  const float* x    = (const float*)d_in[0];
  const int*   eidx = (const int*)d_in[1];
  const float* W    = (const float*)d_in[2];
  const float* bias = (const float*)d_in[3];

  float* ws   = (float*)d_ws;
  float* xt   = ws;                          // B*N*C       = 2,097,152
  float* xn   = xt + (size_t)B * N * C;      // B*N         =    32,768
  float* cent = xn + (size_t)B * N;          // B*NC*C      =    12,800
  float* cn   = cent + B * NC * C;           // 256 (200 used)
  float* umT  = cn + 256;                    // B*NC*N      = 1,638,400
  float* pc   = umT + (size_t)B * NC * N;    // NS*B*NC*C   =   102,400
  float* pu   = pc + (size_t)NS * B * NC * C;// NS*B*NC     =     1,600
  int*   t5   = (int*)(pu + NS * B * NC);    // B*N*TC ints =   163,840
  float* out  = (float*)d_out;               // total ws ~16.2 MB

  k_transpose<<<dim3(B * (N / 64)), dim3(256), 0, stream>>>(x, xt, xn);
  k_init<<<dim3((B * NC * C) / 256), dim3(256), 0, stream>>>(xt, cent, cn);
  for (int it = 0; it < 3; ++it) {
    k_m1<<<dim3(512), dim3(512), 0, stream>>>(xt, xn, cent, cn, umT);
    k_m2<<<dim3(B * NKG * NS), dim3(1024), 0, stream>>>(umT, xt, pc, pu);
    k_m3<<<dim3((B * NC * C) / 256), dim3(256), 0, stream>>>(pc, pu, cent, cn);
  }
  k_top5<<<dim3(512), dim3(512), 0, stream>>>(xt, xn, cent, cn, t5);
  k_out<<<dim3(512), dim3(512), 0, stream>>>(xt, cent, W, t5, eidx, bias, out);
}

// Round 13
// 232.904 us; speedup vs baseline: 1.0344x; 1.0344x over previous
//
#include <hip/hip_runtime.h>

// LHGConv2d: transpose -> FCM (3 iters) -> top5 -> fused edge/cluster/linear.
// R3: k_m2 16-wave blocks 71->19us. R5: k_m1/top5 cluster-sliced. VERIFIED.
// R9: k_out load-batching 59->46us. R10 k_out phase-B s_load matvec: kept.
// R11: umT layout regressed ~12us (unattributed m1/m2 split). R12: DELETE the
//      um global round-trip: fuse m1+m2 into k_fcm (u + xt tile in LDS,
//      per-64-point-chunk partials, 128 deterministic slices).

constexpr int B  = 4;
constexpr int C  = 64;
constexpr int N  = 8192;
constexpr int KE = 16;    // graph neighbors
constexpr int OC = 64;
constexpr int NC = 50;    // num_clusters
constexpr int TC = 5;     // top_clusters
constexpr int C3 = 192;   // 3*C
constexpr int NSL = 128;  // partial slices (= n-chunks per batch)
constexpr float FEPS = 1e-8f;

// ---------------------------------------------------------------- transpose
__global__ __launch_bounds__(256) void k_transpose(const float* __restrict__ x,
                                                   float* __restrict__ xt,
                                                   float* __restrict__ xn) {
  __shared__ float tile[64][65];           // +1 pad: conflict-free transpose
  int b  = blockIdx.x >> 7;                // 128 tiles per batch
  int n0 = (blockIdx.x & 127) << 6;
  int tid = threadIdx.x;
  int nl = tid & 63, cq = tid >> 6;
#pragma unroll
  for (int r = 0; r < 16; ++r) {
    int cc = r * 4 + cq;
    tile[cc][nl] = x[((size_t)b * C + cc) * N + n0 + nl];
  }
  __syncthreads();
  int cl = tid & 63, nq = tid >> 6;
#pragma unroll
  for (int r = 0; r < 16; ++r) {
    int nr = r * 4 + nq;
    xt[((size_t)b * N + n0 + nr) * C + cl] = tile[cl][nr];
  }
  if (tid < 64) {
    float s = 0.f;
#pragma unroll
    for (int cc = 0; cc < 64; ++cc) { float v = tile[cc][tid]; s = fmaf(v, v, s); }
    xn[(size_t)b * N + n0 + tid] = s;
  }
}

// ---------------------------------------------------------------- init cent
__global__ __launch_bounds__(256) void k_init(const float* __restrict__ xt,
                                              float* __restrict__ cent,
                                              float* __restrict__ cn) {
  int i = blockIdx.x * 256 + threadIdx.x;  // 0 .. B*NC*C-1 (12800)
  int lane = threadIdx.x & 63;
  int ccol = i & 63;
  int row  = i >> 6;                       // b*NC + k
  int k = row % NC, b = row / NC;
  int src = (k * (N - 1)) / (NC - 1);      // linspace().astype(int32)
  float v = xt[((size_t)b * N + src) * C + ccol];
  cent[i] = v;
  float sq = v * v;
#pragma unroll
  for (int off = 32; off; off >>= 1) sq += __shfl_down(sq, off, 64);
  if (lane == 0) cn[row] = sq;
}

// ---------------------------------------------------------------- fused FCM step
// Phase 1 (lane=point): k_m1's cluster-sliced dots -> u into LDS (identical
// arithmetic/order to R5's k_m1). Phase 2 (lane=c): per-chunk partial
// centroid accumulation from LDS (u broadcast, xt tile conflict-free).
// 512 blocks x 8 waves; partial slice = chunk (0..127), fixed-order later.
__global__ __launch_bounds__(512) void k_fcm(const float* __restrict__ xt,
                                             const float* __restrict__ xn,
                                             const float* __restrict__ cent,
                                             const float* __restrict__ cn,
                                             float* __restrict__ pc,
                                             float* __restrict__ pu) {
  __shared__ float s_xt[64][68];           // 17.4 KB; stride 68: 16B-aligned f4,
                                           // phase-2 read bank (4n+c)%32 conflict-free
  __shared__ float s_u[NC][64];            // 12.8 KB
  __shared__ float s_ps[8][64];            // 2 KB
  int gid = blockIdx.x;                    // 512 blocks
  int xcd = gid & 7;
  int b = xcd >> 1;                        // 2 XCDs per batch
  int chunk = ((gid >> 3) << 1) + (xcd & 1);  // 0..127
  int n0 = chunk << 6;                     // 64 points
  int w = __builtin_amdgcn_readfirstlane((int)threadIdx.x >> 6);  // 0..7
  int lane = threadIdx.x & 63;
  int n = n0 + lane;
  int base = (w < 2) ? 7 * w : 14 + 6 * (w - 2);
  int cnt  = (w < 2) ? 7 : 6;
  const float* xr = xt + ((size_t)b * N + n) * C;
  const float* cb = cent + b * NC * C;
  float dot[7];
#pragma unroll
  for (int j = 0; j < 7; ++j) dot[j] = 0.f;
  for (int c4 = 0; c4 < C; c4 += 4) {
    float4 xv = *(const float4*)(xr + c4);
    if (w == 0) *(float4*)(&s_xt[lane][c4]) = xv;   // stage tile once
#pragma unroll
    for (int j = 0; j < 7; ++j) {
      int kk = base + j; kk = (kk < NC) ? kk : 0;  // uniform clamp (wave 7, j=6)
      float4 cv = *(const float4*)(cb + kk * C + c4);  // uniform -> s_load
      dot[j] = fmaf(xv.x, cv.x, dot[j]);
      dot[j] = fmaf(xv.y, cv.y, dot[j]);
      dot[j] = fmaf(xv.z, cv.z, dot[j]);
      dot[j] = fmaf(xv.w, cv.w, dot[j]);
    }
  }
  float xnv = xn[(size_t)b * N + n];
  const float* cnb = cn + b * NC;
  float inv[7];
  float psum = 0.f;
#pragma unroll
  for (int j = 0; j < 7; ++j) {
    int kk = base + j; kk = (kk < NC) ? kk : 0;
    float d2 = fmaf(-2.f, dot[j], xnv + cnb[kk]);
    d2 = fmaxf(d2, FEPS);
    float iv = 1.f / d2;
    inv[j] = iv;
    psum += (j < cnt) ? iv : 0.f;
  }
  s_ps[w][lane] = psum;
  __syncthreads();
  float ssum = 0.f;
#pragma unroll
  for (int ww = 0; ww < 8; ++ww) ssum += s_ps[ww][lane];  // fixed order
  float s2i = 1.f / (ssum * ssum);
#pragma unroll
  for (int j = 0; j < 7; ++j)
    if (j < cnt) s_u[base + j][lane] = inv[j] * inv[j] * s2i;  // 2-way (free)
  __syncthreads();
  // ---- phase 2: lane=c; acc[k][c] += u[k][n] * xt[n][c] over 64 points ----
  int c = lane;
  float acc[7], ua[7];
#pragma unroll
  for (int j = 0; j < 7; ++j) { acc[j] = 0.f; ua[j] = 0.f; }
  for (int nn = 0; nn < 64; ++nn) {
    float xv = s_xt[nn][c];                // conflict-free row
#pragma unroll
    for (int j = 0; j < 7; ++j) {
      int kk = base + j; kk = (kk < NC) ? kk : 0;
      float u = s_u[kk][nn];               // wave-uniform -> LDS broadcast
      acc[j] = fmaf(u, xv, acc[j]);
      ua[j] += u;
    }
  }
  float* pcb = pc + (((size_t)chunk * (B * NC) + b * NC + base)) * C + c;
#pragma unroll
  for (int j = 0; j < 7; ++j)
    if (j < cnt) pcb[(size_t)j * C] = acc[j];  // coalesced 256B rows
  if (lane == 0) {
#pragma unroll
    for (int j = 0; j < 7; ++j)
      if (j < cnt) pu[(size_t)chunk * (B * NC) + b * NC + base + j] = ua[j];
  }
}

// ---------------------------------------------------------------- reduce+norm
// cent = sum_{s=0..127} pc[s] / (sum pu[s] + EPS); fixed ascending order.
__global__ __launch_bounds__(256) void k_m3(const float* __restrict__ pc,
                                            const float* __restrict__ pu,
                                            float* __restrict__ cent,
                                            float* __restrict__ cn) {
  int i = blockIdx.x * 256 + threadIdx.x;  // 12800
  int lane = threadIdx.x & 63;
  int row = i >> 6;
  float tot = 0.f;
#pragma unroll 16
  for (int s = 0; s < NSL; ++s) tot += pc[(size_t)s * (B * NC * C) + i];
  float us = 0.f;
#pragma unroll 16
  for (int s = 0; s < NSL; ++s) us += pu[(size_t)s * (B * NC) + row];
  float v = tot / (us + FEPS);
  cent[i] = v;
  float sq = v * v;
#pragma unroll
  for (int off = 32; off; off >>= 1) sq += __shfl_down(sq, off, 64);
  if (lane == 0) cn[row] = sq;
}

// ---------------------------------------------------------------- top-5
__global__ __launch_bounds__(512) void k_top5(const float* __restrict__ xt,
                                              const float* __restrict__ xn,
                                              const float* __restrict__ cent,
                                              const float* __restrict__ cn,
                                              int* __restrict__ t5) {
  int gid = blockIdx.x;                    // 512 blocks
  int xcd = gid & 7;
  int b = xcd >> 1;
  int chunk = ((gid >> 3) << 1) + (xcd & 1);  // 0..127
  int n0 = chunk << 6;
  int w = __builtin_amdgcn_readfirstlane((int)threadIdx.x >> 6);  // 0..7
  int lane = threadIdx.x & 63;
  int n = n0 + lane;
  int base = (w < 2) ? 7 * w : 14 + 6 * (w - 2);
  int cnt  = (w < 2) ? 7 : 6;
  const float* xr = xt + ((size_t)b * N + n) * C;
  const float* cb = cent + b * NC * C;
  float dot[7];
#pragma unroll
  for (int j = 0; j < 7; ++j) dot[j] = 0.f;
  for (int c4 = 0; c4 < C; c4 += 4) {
    float4 xv = *(const float4*)(xr + c4);
#pragma unroll
    for (int j = 0; j < 7; ++j) {
      int kk = base + j; kk = (kk < NC) ? kk : 0;
      float4 cv = *(const float4*)(cb + kk * C + c4);  // uniform -> s_load
      dot[j] = fmaf(xv.x, cv.x, dot[j]);
      dot[j] = fmaf(xv.y, cv.y, dot[j]);
      dot[j] = fmaf(xv.z, cv.z, dot[j]);
      dot[j] = fmaf(xv.w, cv.w, dot[j]);
    }
  }
  float xnv = xn[(size_t)b * N + n];
  const float* cnb = cn + b * NC;
  __shared__ float s_inv[NC][65];          // 13 KiB; [k][point]
#pragma unroll
  for (int j = 0; j < 7; ++j) {
    int kk = base + j; kk = (kk < NC) ? kk : 0;
    float d2 = fmaxf(fmaf(-2.f, dot[j], xnv + cnb[kk]), FEPS);
    float iv = 1.f / d2;
    if (j < cnt) s_inv[base + j][lane] = iv;
  }
  __syncthreads();
  if (w == 0) {
    float v[NC];
#pragma unroll
    for (int k = 0; k < NC; ++k) v[k] = s_inv[k][lane];  // conflict-free row read
    unsigned long long taken = 0ull;
    int* tp = t5 + ((size_t)b * N + n) * TC;
#pragma unroll
    for (int t = 0; t < TC; ++t) {
      float best = -1.f;
      int bi = 0;
#pragma unroll
      for (int k = 0; k < NC; ++k) {
        bool ok = (((taken >> k) & 1ull) == 0ull) && (v[k] > best);
        best = ok ? v[k] : best;
        bi   = ok ? k : bi;
      }
      taken |= (1ull << bi);
      tp[t] = bi;
    }
  }
}

// ---------------------------------------------------------------- fused output
// Phase A (lane=c, batched gathers) -> s_feat. Phase B (lane=n): wave wv
// computes o in [8wv,8wv+8) over 64 points; W/bias wave-uniform s_load.
__global__ __launch_bounds__(512, 4) void k_out(const float* __restrict__ xt,
                                                const float* __restrict__ cent,
                                                const float* __restrict__ W,
                                                const int* __restrict__ t5,
                                                const int* __restrict__ eidx,
                                                const float* __restrict__ bias,
                                                float* __restrict__ out) {
  __shared__ float s_feat[C3][65];         // 49.9 KB; 2-way alias (free)
  int tid = threadIdx.x;
  int gid = blockIdx.x;                    // 512 blocks
  int xcd = gid & 7;
  int b = xcd >> 1;
  int chunk = ((gid >> 3) << 1) + (xcd & 1);  // 0..127 (64 points each)
  int wv = __builtin_amdgcn_readfirstlane(tid >> 6);  // 0..7
  int lane = tid & 63;
  int n0 = chunk * 64;
  int nw0 = n0 + wv * 8;                   // phase-A points for this wave
  const float* xtb = xt + ((size_t)b * N) * C;
  const float* cb  = cent + b * NC * C;
  const int* e0b = eidx + ((size_t)b * N) * KE;
  const int* e1b = eidx + ((size_t)(B + b) * N) * KE;
  int c = lane;
  int fr = wv * 8;
#pragma unroll
  for (int j = 0; j < 8; ++j) {
    int n = nw0 + j;
    const int* p0 = e0b + (size_t)n * KE;  // uniform -> s_load
    const int* p1 = e1b + (size_t)n * KE;
    const int* tp = t5 + ((size_t)b * N + n) * TC;
    float x0 = xtb[(size_t)n * C + c];
    float g0[KE], g1[KE];
#pragma unroll
    for (int k = 0; k < KE; ++k) {
      g0[k] = xtb[(size_t)p0[k] * C + c];
      g1[k] = xtb[(size_t)p1[k] * C + c];
    }
    float cv[TC];
#pragma unroll
    for (int t = 0; t < TC; ++t) cv[t] = cb[(size_t)tp[t] * C + c];
    float m1 = g0[0] - g1[0];
#pragma unroll
    for (int k = 1; k < KE; ++k) m1 = fmaxf(m1, g0[k] - g1[k]);
    float cm = cv[0];
#pragma unroll
    for (int t = 1; t < TC; ++t) cm = fmaxf(cm, cv[t]);
    s_feat[3 * c + 0][fr + j] = x0;
    s_feat[3 * c + 1][fr + j] = m1;
    s_feat[3 * c + 2][fr + j] = cm - x0;
  }
  __syncthreads();
  int o0 = wv * 8;
  float acc[8];
#pragma unroll
  for (int oj = 0; oj < 8; ++oj) acc[oj] = bias[o0 + oj];  // uniform -> s_load
#pragma unroll 4
  for (int f = 0; f < C3; ++f) {
    float v = s_feat[f][lane];
#pragma unroll
    for (int oj = 0; oj < 8; ++oj)
      acc[oj] = fmaf(W[(size_t)(o0 + oj) * C3 + f], v, acc[oj]);  // W: s_load
  }
  float* ob = out + ((size_t)b * OC + o0) * N + n0 + lane;
#pragma unroll
  for (int oj = 0; oj < 8; ++oj)
    ob[(size_t)oj * N] = fmaxf(acc[oj], 0.f);  // coalesced 256B per o
}

// ----------------------------------------------------------------------------
extern "C" void kernel_launch(void* const* d_in, const int* in_sizes, int n_in,
                              void* d_out, int out_size, void* d_ws, size_t ws_size,
                              hipStream_t stream) {
  const float* x    = (const float*)d_in[0];
  const int*   eidx = (const int*)d_in[1];
  const float* W    = (const float*)d_in[2];
  const float* bias = (const float*)d_in[3];

  float* ws   = (float*)d_ws;
  float* xt   = ws;                          // B*N*C        = 2,097,152
  float* xn   = xt + (size_t)B * N * C;      // B*N          =    32,768
  float* cent = xn + (size_t)B * N;          // B*NC*C       =    12,800
  float* cn   = cent + B * NC * C;           // 256 (200 used)
  float* pc   = cn + 256;                    // NSL*B*NC*C   = 1,638,400
  float* pu   = pc + (size_t)NSL * B * NC * C;// NSL*B*NC    =    25,600
  int*   t5   = (int*)(pu + (size_t)NSL * B * NC);  // B*N*TC = 163,840 ints
  float* out  = (float*)d_out;               // total ws ~15.9 MB

  k_transpose<<<dim3(B * (N / 64)), dim3(256), 0, stream>>>(x, xt, xn);
  k_init<<<dim3((B * NC * C) / 256), dim3(256), 0, stream>>>(xt, cent, cn);
  for (int it = 0; it < 3; ++it) {
    k_fcm<<<dim3(512), dim3(512), 0, stream>>>(xt, xn, cent, cn, pc, pu);
    k_m3<<<dim3((B * NC * C) / 256), dim3(256), 0, stream>>>(pc, pu, cent, cn);
  }
  k_top5<<<dim3(512), dim3(512), 0, stream>>>(xt, xn, cent, cn, t5);
  k_out<<<dim3(512), dim3(512), 0, stream>>>(xt, cent, W, t5, eidx, bias, out);
}

// Round 15
// 227.203 us; speedup vs baseline: 1.0603x; 1.0251x over previous
//
#include <hip/hip_runtime.h>

// LHGConv2d: transpose -> FCM (3 iters) -> fused top5+edge/cluster/linear.
// R3: k_m2 16-wave blocks 71->19us. R5: cluster-sliced waves. VERIFIED.
// R9: k_out load-batching 59->46us. R12: m1+m2 fused (k_fcm), um deleted.
// R13: totals across FCM variants within noise (228-241); attribution blind
//      below harness 42us fills. This round: fuse top5 INTO k_out (phase 0
//      dots -> LDS select -> s_t5; t5 global round-trip + launch deleted);
//      k_fcm pu via phase-1 shuffle reduce.

constexpr int B  = 4;
constexpr int C  = 64;
constexpr int N  = 8192;
constexpr int KE = 16;    // graph neighbors
constexpr int OC = 64;
constexpr int NC = 50;    // num_clusters
constexpr int TC = 5;     // top_clusters
constexpr int C3 = 192;   // 3*C
constexpr int NSL = 128;  // partial slices (= n-chunks per batch)
constexpr float FEPS = 1e-8f;

// ---------------------------------------------------------------- transpose
__global__ __launch_bounds__(256) void k_transpose(const float* __restrict__ x,
                                                   float* __restrict__ xt,
                                                   float* __restrict__ xn) {
  __shared__ float tile[64][65];           // +1 pad: conflict-free transpose
  int b  = blockIdx.x >> 7;                // 128 tiles per batch
  int n0 = (blockIdx.x & 127) << 6;
  int tid = threadIdx.x;
  int nl = tid & 63, cq = tid >> 6;
#pragma unroll
  for (int r = 0; r < 16; ++r) {
    int cc = r * 4 + cq;
    tile[cc][nl] = x[((size_t)b * C + cc) * N + n0 + nl];
  }
  __syncthreads();
  int cl = tid & 63, nq = tid >> 6;
#pragma unroll
  for (int r = 0; r < 16; ++r) {
    int nr = r * 4 + nq;
    xt[((size_t)b * N + n0 + nr) * C + cl] = tile[cl][nr];
  }
  if (tid < 64) {
    float s = 0.f;
#pragma unroll
    for (int cc = 0; cc < 64; ++cc) { float v = tile[cc][tid]; s = fmaf(v, v, s); }
    xn[(size_t)b * N + n0 + tid] = s;
  }
}

// ---------------------------------------------------------------- init cent
__global__ __launch_bounds__(256) void k_init(const float* __restrict__ xt,
                                              float* __restrict__ cent,
                                              float* __restrict__ cn) {
  int i = blockIdx.x * 256 + threadIdx.x;  // 0 .. B*NC*C-1 (12800)
  int lane = threadIdx.x & 63;
  int ccol = i & 63;
  int row  = i >> 6;                       // b*NC + k
  int k = row % NC, b = row / NC;
  int src = (k * (N - 1)) / (NC - 1);      // linspace().astype(int32)
  float v = xt[((size_t)b * N + src) * C + ccol];
  cent[i] = v;
  float sq = v * v;
#pragma unroll
  for (int off = 32; off; off >>= 1) sq += __shfl_down(sq, off, 64);
  if (lane == 0) cn[row] = sq;
}

// ---------------------------------------------------------------- fused FCM step
// Phase 1 (lane=point): cluster-sliced dots -> u into LDS; pu via 64-lane
// shuffle reduce (tree order: eps-drift only). Phase 2 (lane=c): per-chunk
// partial centroid accumulation from LDS.
__global__ __launch_bounds__(512) void k_fcm(const float* __restrict__ xt,
                                             const float* __restrict__ xn,
                                             const float* __restrict__ cent,
                                             const float* __restrict__ cn,
                                             float* __restrict__ pc,
                                             float* __restrict__ pu) {
  __shared__ float s_xt[64][68];           // 17.4 KB; phase-2 conflict-free
  __shared__ float s_u[NC][64];            // 12.8 KB
  __shared__ float s_ps[8][64];            // 2 KB
  int gid = blockIdx.x;                    // 512 blocks
  int xcd = gid & 7;
  int b = xcd >> 1;                        // 2 XCDs per batch
  int chunk = ((gid >> 3) << 1) + (xcd & 1);  // 0..127
  int n0 = chunk << 6;                     // 64 points
  int w = __builtin_amdgcn_readfirstlane((int)threadIdx.x >> 6);  // 0..7
  int lane = threadIdx.x & 63;
  int n = n0 + lane;
  int base = (w < 2) ? 7 * w : 14 + 6 * (w - 2);
  int cnt  = (w < 2) ? 7 : 6;
  const float* xr = xt + ((size_t)b * N + n) * C;
  const float* cb = cent + b * NC * C;
  float dot[7];
#pragma unroll
  for (int j = 0; j < 7; ++j) dot[j] = 0.f;
  for (int c4 = 0; c4 < C; c4 += 4) {
    float4 xv = *(const float4*)(xr + c4);
    if (w == 0) *(float4*)(&s_xt[lane][c4]) = xv;   // stage tile once
#pragma unroll
    for (int j = 0; j < 7; ++j) {
      int kk = base + j; kk = (kk < NC) ? kk : 0;  // uniform clamp (wave 7, j=6)
      float4 cv = *(const float4*)(cb + kk * C + c4);  // uniform -> s_load
      dot[j] = fmaf(xv.x, cv.x, dot[j]);
      dot[j] = fmaf(xv.y, cv.y, dot[j]);
      dot[j] = fmaf(xv.z, cv.z, dot[j]);
      dot[j] = fmaf(xv.w, cv.w, dot[j]);
    }
  }
  float xnv = xn[(size_t)b * N + n];
  const float* cnb = cn + b * NC;
  float inv[7];
  float psum = 0.f;
#pragma unroll
  for (int j = 0; j < 7; ++j) {
    int kk = base + j; kk = (kk < NC) ? kk : 0;
    float d2 = fmaf(-2.f, dot[j], xnv + cnb[kk]);
    d2 = fmaxf(d2, FEPS);
    float iv = 1.f / d2;
    inv[j] = iv;
    psum += (j < cnt) ? iv : 0.f;
  }
  s_ps[w][lane] = psum;
  __syncthreads();
  float ssum = 0.f;
#pragma unroll
  for (int ww = 0; ww < 8; ++ww) ssum += s_ps[ww][lane];  // fixed order
  float s2i = 1.f / (ssum * ssum);
#pragma unroll
  for (int j = 0; j < 7; ++j) {
    float uval = inv[j] * inv[j] * s2i;
    if (j < cnt) s_u[base + j][lane] = uval;     // 2-way (free)
    float r = (j < cnt) ? uval : 0.f;
#pragma unroll
    for (int off = 32; off; off >>= 1) r += __shfl_down(r, off, 64);
    if (lane == 0 && j < cnt)
      pu[(size_t)chunk * (B * NC) + b * NC + base + j] = r;
  }
  __syncthreads();
  // ---- phase 2: lane=c; acc[k][c] += u[k][n] * xt[n][c] over 64 points ----
  int c = lane;
  float acc[7];
#pragma unroll
  for (int j = 0; j < 7; ++j) acc[j] = 0.f;
#pragma unroll 8
  for (int nn = 0; nn < 64; ++nn) {
    float xv = s_xt[nn][c];                // conflict-free row
#pragma unroll
    for (int j = 0; j < 7; ++j) {
      int kk = base + j; kk = (kk < NC) ? kk : 0;
      float u = s_u[kk][nn];               // wave-uniform -> LDS broadcast
      acc[j] = fmaf(u, xv, acc[j]);
    }
  }
  float* pcb = pc + (((size_t)chunk * (B * NC) + b * NC + base)) * C + c;
#pragma unroll
  for (int j = 0; j < 7; ++j)
    if (j < cnt) pcb[(size_t)j * C] = acc[j];  // coalesced 256B rows
}

// ---------------------------------------------------------------- reduce+norm
__global__ __launch_bounds__(256) void k_m3(const float* __restrict__ pc,
                                            const float* __restrict__ pu,
                                            float* __restrict__ cent,
                                            float* __restrict__ cn) {
  int i = blockIdx.x * 256 + threadIdx.x;  // 12800
  int lane = threadIdx.x & 63;
  int row = i >> 6;
  float tot = 0.f;
#pragma unroll 16
  for (int s = 0; s < NSL; ++s) tot += pc[(size_t)s * (B * NC * C) + i];
  float us = 0.f;
#pragma unroll 16
  for (int s = 0; s < NSL; ++s) us += pu[(size_t)s * (B * NC) + row];
  float v = tot / (us + FEPS);
  cent[i] = v;
  float sq = v * v;
#pragma unroll
  for (int off = 32; off; off >>= 1) sq += __shfl_down(sq, off, 64);
  if (lane == 0) cn[row] = sq;
}

// ---------------------------------------------------------------- fused top5+output
// Phase 0 (= old k_top5): cluster-sliced dots -> s_inv (aliased onto s_feat
// rows 0..49; dead before phase A overwrites), wave 0 selects -> s_t5 (LDS).
// Phase A (lane=c): batched gathers, t5 from LDS broadcast -> s_feat.
// Phase B (lane=n): wave wv computes o in [8wv,8wv+8); W/bias s_load.
__global__ __launch_bounds__(512, 4) void k_out5(const float* __restrict__ xt,
                                                 const float* __restrict__ xn,
                                                 const float* __restrict__ cent,
                                                 const float* __restrict__ cn,
                                                 const float* __restrict__ W,
                                                 const int* __restrict__ eidx,
                                                 const float* __restrict__ bias,
                                                 float* __restrict__ out) {
  __shared__ float s_feat[C3][65];         // 49.9 KB; rows 0..49 alias s_inv
  __shared__ int s_t5[64][TC];             // 1.3 KB
  float (*s_inv)[65] = s_feat;             // phase-0 view
  int tid = threadIdx.x;
  int gid = blockIdx.x;                    // 512 blocks
  int xcd = gid & 7;
  int b = xcd >> 1;
  int chunk = ((gid >> 3) << 1) + (xcd & 1);  // 0..127 (64 points each)
  int wv = __builtin_amdgcn_readfirstlane(tid >> 6);  // 0..7
  int lane = tid & 63;
  int n0 = chunk * 64;
  const float* xtb = xt + ((size_t)b * N) * C;
  const float* cb  = cent + b * NC * C;
  // ---- phase 0: membership dots for this chunk's 64 points ----
  {
    int n = n0 + lane;
    int base = (wv < 2) ? 7 * wv : 14 + 6 * (wv - 2);
    int cnt  = (wv < 2) ? 7 : 6;
    const float* xr = xtb + (size_t)n * C;
    float dot[7];
#pragma unroll
    for (int j = 0; j < 7; ++j) dot[j] = 0.f;
    for (int c4 = 0; c4 < C; c4 += 4) {
      float4 xv = *(const float4*)(xr + c4);
#pragma unroll
      for (int j = 0; j < 7; ++j) {
        int kk = base + j; kk = (kk < NC) ? kk : 0;
        float4 cv = *(const float4*)(cb + kk * C + c4);  // uniform -> s_load
        dot[j] = fmaf(xv.x, cv.x, dot[j]);
        dot[j] = fmaf(xv.y, cv.y, dot[j]);
        dot[j] = fmaf(xv.z, cv.z, dot[j]);
        dot[j] = fmaf(xv.w, cv.w, dot[j]);
      }
    }
    float xnv = xn[(size_t)b * N + n];
    const float* cnb = cn + b * NC;
#pragma unroll
    for (int j = 0; j < 7; ++j) {
      int kk = base + j; kk = (kk < NC) ? kk : 0;
      float d2 = fmaxf(fmaf(-2.f, dot[j], xnv + cnb[kk]), FEPS);
      float iv = 1.f / d2;
      if (j < cnt) s_inv[base + j][lane] = iv;
    }
  }
  __syncthreads();
  if (wv == 0) {                           // selection (== lax.top_k ties)
    float v[NC];
#pragma unroll
    for (int k = 0; k < NC; ++k) v[k] = s_inv[k][lane];  // 2-way (free)
    unsigned long long taken = 0ull;
#pragma unroll
    for (int t = 0; t < TC; ++t) {
      float best = -1.f;
      int bi = 0;
#pragma unroll
      for (int k = 0; k < NC; ++k) {
        bool ok = (((taken >> k) & 1ull) == 0ull) && (v[k] > best);
        best = ok ? v[k] : best;
        bi   = ok ? k : bi;
      }
      taken |= (1ull << bi);
      s_t5[lane][t] = bi;
    }
  }
  __syncthreads();                         // s_inv dead from here; s_feat free
  // ---- phase A: gathers (lane=c), 8 points per wave ----
  int nw0 = n0 + wv * 8;
  const int* e0b = eidx + ((size_t)b * N) * KE;
  const int* e1b = eidx + ((size_t)(B + b) * N) * KE;
  int c = lane;
  int fr = wv * 8;
#pragma unroll
  for (int j = 0; j < 8; ++j) {
    int n = nw0 + j;
    const int* p0 = e0b + (size_t)n * KE;  // uniform -> s_load
    const int* p1 = e1b + (size_t)n * KE;
    int t0 = s_t5[fr + j][0], t1 = s_t5[fr + j][1], t2 = s_t5[fr + j][2];
    int t3 = s_t5[fr + j][3], t4 = s_t5[fr + j][4];  // LDS broadcast
    float x0 = xtb[(size_t)n * C + c];
    float g0[KE], g1[KE];
#pragma unroll
    for (int k = 0; k < KE; ++k) {
      g0[k] = xtb[(size_t)p0[k] * C + c];
      g1[k] = xtb[(size_t)p1[k] * C + c];
    }
    float cv0 = cb[(size_t)t0 * C + c], cv1 = cb[(size_t)t1 * C + c];
    float cv2 = cb[(size_t)t2 * C + c], cv3 = cb[(size_t)t3 * C + c];
    float cv4 = cb[(size_t)t4 * C + c];
    float m1 = g0[0] - g1[0];
#pragma unroll
    for (int k = 1; k < KE; ++k) m1 = fmaxf(m1, g0[k] - g1[k]);
    float cm = fmaxf(fmaxf(fmaxf(fmaxf(cv0, cv1), cv2), cv3), cv4);
    s_feat[3 * c + 0][fr + j] = x0;
    s_feat[3 * c + 1][fr + j] = m1;
    s_feat[3 * c + 2][fr + j] = cm - x0;
  }
  __syncthreads();
  // ---- phase B: matvec (lane=n), W/bias wave-uniform s_load ----
  int o0 = wv * 8;
  float acc[8];
#pragma unroll
  for (int oj = 0; oj < 8; ++oj) acc[oj] = bias[o0 + oj];
#pragma unroll 4
  for (int f = 0; f < C3; ++f) {
    float v = s_feat[f][lane];
#pragma unroll
    for (int oj = 0; oj < 8; ++oj)
      acc[oj] = fmaf(W[(size_t)(o0 + oj) * C3 + f], v, acc[oj]);
  }
  float* ob = out + ((size_t)b * OC + o0) * N + n0 + lane;
#pragma unroll
  for (int oj = 0; oj < 8; ++oj)
    ob[(size_t)oj * N] = fmaxf(acc[oj], 0.f);  // coalesced 256B per o
}

// ----------------------------------------------------------------------------
extern "C" void kernel_launch(void* const* d_in, const int* in_sizes, int n_in,
                              void* d_out, int out_size, void* d_ws, size_t ws_size,
                              hipStream_t stream) {
  const float* x    = (const float*)d_in[0];
  const int*   eidx = (const int*)d_in[1];
  const float* W    = (const float*)d_in[2];
  const float* bias = (const float*)d_in[3];

  float* ws   = (float*)d_ws;
  float* xt   = ws;                          // B*N*C        = 2,097,152
  float* xn   = xt + (size_t)B * N * C;      // B*N          =    32,768
  float* cent = xn + (size_t)B * N;          // B*NC*C       =    12,800
  float* cn   = cent + B * NC * C;           // 256 (200 used)
  float* pc   = cn + 256;                    // NSL*B*NC*C   = 1,638,400
  float* pu   = pc + (size_t)NSL * B * NC * C;// NSL*B*NC    =    25,600
  float* out  = (float*)d_out;               // total ws ~15.2 MB

  k_transpose<<<dim3(B * (N / 64)), dim3(256), 0, stream>>>(x, xt, xn);
  k_init<<<dim3((B * NC * C) / 256), dim3(256), 0, stream>>>(xt, cent, cn);
  for (int it = 0; it < 3; ++it) {
    k_fcm<<<dim3(512), dim3(512), 0, stream>>>(xt, xn, cent, cn, pc, pu);
    k_m3<<<dim3((B * NC * C) / 256), dim3(256), 0, stream>>>(pc, pu, cent, cn);
  }
  k_out5<<<dim3(512), dim3(512), 0, stream>>>(xt, xn, cent, cn, W, eidx, bias, out);
}